// Round 4
// baseline (109.592 us; speedup 1.0000x reference)
//
#include <hip/hip_runtime.h>
#include <math.h>

#define TAU_INV (1.0f / 0.07f)
#define KSEL 50
#define KPAD 64      // zero-padded rows 50..63: dot=0 -> exp=1 -> subtract 14
#define NPIX 8192
#define CCH 128
#define HWSZ 4096
#define NCLS 4
#define EPSL 1e-8f
#define NBINS 1026
#define PXT 32       // pixels per loss block
#define SROW 132     // LDS row stride in floats

// ---------------------------------------------------------------------------
// Kernel A: blocks 0..3 = per-class top-50 (inline seg/softmax from logits;
// bitmask+scan bucketing, no serialized atomics; winners kept in LDS; tail
// phase gathers + normalizes the 50 selected negative columns into compact
// nnsel).  Blocks 4..259 = L2-normalize+transpose input & positive only
// (negative tensor no longer normalized: 97.5% of that work was unused).
// Grid = 260 blocks ~= one CU-wave, no tail.
// ---------------------------------------------------------------------------
__global__ void __launch_bounds__(256) prep_kernel(
        const float* __restrict__ input, const float* __restrict__ positive,
        const float* __restrict__ negative,
        const float* __restrict__ ilog, const float* __restrict__ nlog,
        float* __restrict__ ni, float* __restrict__ np_,
        float* __restrict__ nnsel,
        int* __restrict__ perm, int* __restrict__ cnt,
        float* __restrict__ out) {
    __shared__ union {
        struct {                       // norm+transpose path (34560 B)
            float tile[CCH][65];
            float partial[4][64];
            float invn[64];
        } a;
        struct {                       // topk path (~21.2 KB)
            unsigned hist[NBINS];
            unsigned coarse[33];
            unsigned long long cand[2048];
            unsigned wsum[4];
            int topk_l[KPAD];
            unsigned above_cnt, cand_cnt;
            int sB, sc0;
        } b;
    } sm;

    int t = threadIdx.x;
    int bid = blockIdx.x;

    if (bid == 0 && t == 0) out[0] = 0.0f;

    if (bid >= NCLS) {
        // ---- norm+transpose path: input (blk 0..127), positive (128..255) ----
        int blk = bid - NCLS;
        int tensor = blk >> 7, chunk = blk & 127;
        const float* src = (tensor == 0) ? input : positive;
        float*       dst = (tensor == 0) ? ni    : np_;

        int n0 = chunk * 64;
        int b = n0 >> 12, hw0 = n0 & (HWSZ - 1);
        const float* base = src + (size_t)b * CCH * HWSZ + hw0;

        // load: float4 along hw; 4 scalar LDS writes (conflict-free, stride 65)
        #pragma unroll
        for (int i = 0; i < 8; ++i) {
            int lin = t + i * 256;
            int cc = lin >> 4, hwq = (lin & 15) * 4;
            float4 v = *(const float4*)&base[(size_t)cc * HWSZ + hwq];
            sm.a.tile[cc][hwq + 0] = v.x; sm.a.tile[cc][hwq + 1] = v.y;
            sm.a.tile[cc][hwq + 2] = v.z; sm.a.tile[cc][hwq + 3] = v.w;
        }
        __syncthreads();

        int nof = t & 63, part = t >> 6;
        float s = 0.f;
        #pragma unroll
        for (int j = 0; j < 32; ++j) {
            float v = sm.a.tile[part * 32 + j][nof];
            s += v * v;
        }
        sm.a.partial[part][nof] = s;
        __syncthreads();
        if (t < 64) {
            float tot = sm.a.partial[0][t] + sm.a.partial[1][t] +
                        sm.a.partial[2][t] + sm.a.partial[3][t];
            sm.a.invn[t] = 1.0f / fmaxf(sqrtf(tot), 1e-12f);
        }
        __syncthreads();

        // store: gather 4 consecutive channels -> one float4 coalesced store
        #pragma unroll
        for (int i = 0; i < 8; ++i) {
            int lin = t + i * 256;
            int nf = lin >> 5, cq = (lin & 31) * 4;
            float inv = sm.a.invn[nf];
            float4 o;
            o.x = sm.a.tile[cq + 0][nf] * inv;
            o.y = sm.a.tile[cq + 1][nf] * inv;
            o.z = sm.a.tile[cq + 2][nf] * inv;
            o.w = sm.a.tile[cq + 3][nf] * inv;
            *(float4*)&dst[(size_t)(n0 + nf) * CCH + cq] = o;
        }
        return;
    }

    // ---- topk path: class c, seg/softmax recomputed inline ----
    int c = bid;

    for (int i = t; i < NBINS; i += 256) sm.b.hist[i] = 0;
    if (t < 33) sm.b.coarse[t] = 0;
    if (t == 0) { sm.b.above_cnt = 0; sm.b.cand_cnt = 0; }
    __syncthreads();

    // Phase 1: inline seg -> histogram + same-class membership bitmask.
    // 256 threads x 8 segments x 4 px = 8192 pixels; bit (s*4+j) of `mask`
    // marks pixel (t + s*256)*4 + j as seg_input == c.
    unsigned keys[32];
    unsigned mask = 0u;
    #pragma unroll
    for (int s = 0; s < 8; ++s) {
        int i4 = (t + s * 256) * 4;
        int b = i4 >> 12, hw = i4 & (HWSZ - 1);

        const float* pi = ilog + (size_t)b * NCLS * HWSZ + hw;
        float4 a0 = *(const float4*)&pi[0];
        float4 a1 = *(const float4*)&pi[HWSZ];
        float4 a2 = *(const float4*)&pi[2 * HWSZ];
        float4 a3 = *(const float4*)&pi[3 * HWSZ];
        const float* pn = nlog + (size_t)b * NCLS * HWSZ + hw;
        float4 b0 = *(const float4*)&pn[0];
        float4 b1 = *(const float4*)&pn[HWSZ];
        float4 b2 = *(const float4*)&pn[2 * HWSZ];
        float4 b3 = *(const float4*)&pn[3 * HWSZ];

        const float* A0 = (const float*)&a0; const float* A1 = (const float*)&a1;
        const float* A2 = (const float*)&a2; const float* A3 = (const float*)&a3;
        const float* B0 = (const float*)&b0; const float* B1 = (const float*)&b1;
        const float* B2 = (const float*)&b2; const float* B3 = (const float*)&b3;
        #pragma unroll
        for (int j = 0; j < 4; ++j) {
            // input argmax -> same-class membership
            float l0 = A0[j], l1 = A1[j], l2 = A2[j], l3 = A3[j];
            int bi = 0; float bv = l0;
            if (l1 > bv) { bv = l1; bi = 1; }
            if (l2 > bv) { bv = l2; bi = 2; }
            if (l3 > bv) { bv = l3; bi = 3; }
            if (bi == c) mask |= (1u << (s * 4 + j));
            // negative argmax + max softmax prob
            float m0 = B0[j], m1 = B1[j], m2 = B2[j], m3 = B3[j];
            int ci = 0; float cv = m0;
            if (m1 > cv) { cv = m1; ci = 1; }
            if (m2 > cv) { cv = m2; ci = 2; }
            if (m3 > cv) { cv = m3; ci = 3; }
            float ssum = expf(m0 - cv) + expf(m1 - cv) + expf(m2 - cv) + expf(m3 - cv);
            float npv = 1.0f / ssum;

            float v = (ci != c) ? npv : 0.0f;
            unsigned key = __float_as_uint(v);
            keys[s * 4 + j] = key;
            int bin = (key < 0x3E800000u) ? 0 : (int)(1u + ((key - 0x3E800000u) >> 14));
            atomicAdd(&sm.b.hist[bin], 1u);
        }
    }

    // Phase 1b: atomic-free bucketing via block exclusive scan of popcounts.
    {
        int cnt_t = __popc(mask);
        int lane = t & 63, wv = t >> 6;
        int x = cnt_t;
        #pragma unroll
        for (int off = 1; off < 64; off <<= 1) {
            int o = __shfl_up(x, off);
            if (lane >= off) x += o;
        }
        if (lane == 63) sm.b.wsum[wv] = (unsigned)x;
        __syncthreads();
        int base = x - cnt_t;
        for (int ww = 0; ww < wv; ++ww) base += (int)sm.b.wsum[ww];
        unsigned mm = mask; int k = 0;
        while (mm) {
            int bit = __ffs(mm) - 1; mm &= (mm - 1);
            int s2 = bit >> 2, j2 = bit & 3;
            perm[c * NPIX + base + k] = (t + s2 * 256) * 4 + j2;
            ++k;
        }
        if (t == 0) cnt[c] = (int)(sm.b.wsum[0] + sm.b.wsum[1] +
                                   sm.b.wsum[2] + sm.b.wsum[3]);
    }
    __syncthreads();

    // Phase 2a: coarse sums (32 bins per chunk)
    for (int i = t; i < NBINS; i += 256) atomicAdd(&sm.b.coarse[i >> 5], sm.b.hist[i]);
    __syncthreads();

    // Phase 2b: two-level serial scan from the top (proven logic)
    if (t == 0) {
        unsigned cum = 0; int j = 32;
        for (; j > 0; --j) {
            unsigned h = sm.b.coarse[j];
            if (cum + h >= KSEL) break;
            cum += h;
        }
        int hi = j * 32 + 31; if (hi > NBINS - 1) hi = NBINS - 1;
        int B = 0;
        for (int b = hi; b >= j * 32; --b) {
            unsigned h = sm.b.hist[b];
            if (cum + h >= KSEL) { B = b; break; }
            cum += h;
        }
        sm.b.sB = B; sm.b.sc0 = (int)cum;   // cum = count strictly above bin B
    }
    __syncthreads();
    int B = sm.b.sB, c0 = sm.b.sc0;

    // Phase 3: emit definite winners (to LDS); collect boundary-bin candidates
    #pragma unroll
    for (int s = 0; s < 8; ++s) {
        #pragma unroll
        for (int j = 0; j < 4; ++j) {
            unsigned key = keys[s * 4 + j];
            int bin = (key < 0x3E800000u) ? 0 : (int)(1u + ((key - 0x3E800000u) >> 14));
            int i = (t + s * 256) * 4 + j;
            if (bin > B) {
                unsigned pos = atomicAdd(&sm.b.above_cnt, 1u);
                sm.b.topk_l[pos] = i;
            } else if (bin == B) {
                unsigned jj = atomicAdd(&sm.b.cand_cnt, 1u);
                if (jj < 2048)
                    sm.b.cand[jj] = ((unsigned long long)key << 32) |
                                    (unsigned long long)(0xFFFFFFFFu - (unsigned)i);
            }
        }
    }
    __syncthreads();

    // Phase 4: wave 0 picks remaining (50 - c0) best boundary candidates
    int m = KSEL - c0;
    int cb = (int)sm.b.cand_cnt; if (cb > 2048) cb = 2048;
    if (t < 64) {
        for (int r = 0; r < m; ++r) {
            unsigned long long best = 0;
            for (int j = t; j < cb; j += 64) {
                unsigned long long v = sm.b.cand[j];
                if (v > best) best = v;
            }
            #pragma unroll
            for (int off = 32; off; off >>= 1) {
                unsigned long long o = __shfl_xor(best, off);
                if (o > best) best = o;
            }
            if (t == 0) sm.b.topk_l[c0 + r] =
                (int)(0xFFFFFFFFu - (unsigned)(best & 0xFFFFFFFFull));
            for (int j = t; j < cb; j += 64)
                if (sm.b.cand[j] == best) sm.b.cand[j] = 0;
        }
    }
    __syncthreads();

    // Phase 5: gather + normalize the 50 selected negative columns into
    // compact nnsel[c*KSEL + row][CCH].  4 threads per row, 32 ch each;
    // quad-shuffle reduce for the squared norm (quads never straddle waves).
    {
        int row = t >> 2;
        int ch0 = (t & 3) * 32;
        if (row < KSEL) {
            int px = sm.b.topk_l[row];
            int b = px >> 12, hw = px & (HWSZ - 1);
            const float* src = negative + (size_t)b * CCH * HWSZ + hw;
            float vals[32]; float ss = 0.f;
            #pragma unroll
            for (int k2 = 0; k2 < 32; ++k2) {
                float v = src[(size_t)(ch0 + k2) * HWSZ];
                vals[k2] = v; ss += v * v;
            }
            ss += __shfl_xor(ss, 1);
            ss += __shfl_xor(ss, 2);
            float inv = 1.0f / fmaxf(sqrtf(ss), 1e-12f);
            float* dst = nnsel + (size_t)(c * KSEL + row) * CCH + ch0;
            #pragma unroll
            for (int k2 = 0; k2 < 32; ++k2) dst[k2] = vals[k2] * inv;
        }
    }
}

// ---------------------------------------------------------------------------
// Kernel B: same-class GEMM-style loss.  Block = 32 pixels of one class.
// Thread (ktid 0..7, pxid 0..31) owns 8 k-rows x 1 pixel; dots accumulate in
// registers over all 128 channels.  S-stage now reads the compact pre-
// normalized nnsel rows (contiguous, no index indirection).
// ---------------------------------------------------------------------------
__global__ void __launch_bounds__(256) loss_kernel(
        const float* __restrict__ ni, const float* __restrict__ npos,
        const float* __restrict__ nnsel,
        const int* __restrict__ perm, const int* __restrict__ cnt,
        float* __restrict__ out) {
    __shared__ float Sl[KPAD * SROW];   // 33792 B
    __shared__ float Xl[PXT * SROW];    // 16896 B
    __shared__ float Pl[PXT * SROW];    // 16896 B
    __shared__ float bsum[4];

    int c = blockIdx.y;
    int count = cnt[c];
    int start = blockIdx.x * PXT;
    if (start >= count) return;
    int t = threadIdx.x;

    // stage S: 4 threads per row, 32 ch each (rows 50..63 zeroed)
    {
        int row = t >> 2;
        int ch0 = (t & 3) * 32;
        float* dst = &Sl[row * SROW + ch0];
        if (row < KSEL) {
            const float* src = nnsel + (size_t)(c * KSEL + row) * CCH + ch0;
            #pragma unroll
            for (int i = 0; i < 8; ++i)
                ((float4*)dst)[i] = ((const float4*)src)[i];
        } else {
            float4 z = make_float4(0.f, 0.f, 0.f, 0.f);
            #pragma unroll
            for (int i = 0; i < 8; ++i)
                ((float4*)dst)[i] = z;
        }
    }
    // stage X, P: 8 threads per pixel row, 16 ch each
    {
        int row = t >> 3;
        int slot = start + row;
        int px = perm[c * NPIX + ((slot < count) ? slot : start)];
        int ch0 = (t & 7) * 16;
        const float* sx = ni + (size_t)px * CCH + ch0;
        const float* sp = npos + (size_t)px * CCH + ch0;
        float* dx = &Xl[row * SROW + ch0];
        float* dp = &Pl[row * SROW + ch0];
        #pragma unroll
        for (int i = 0; i < 4; ++i) {
            ((float4*)dx)[i] = ((const float4*)sx)[i];
            ((float4*)dp)[i] = ((const float4*)sp)[i];
        }
    }
    __syncthreads();

    int ktid = t & 7, pxid = t >> 3;
    float acc_i[8] = {0.f, 0.f, 0.f, 0.f, 0.f, 0.f, 0.f, 0.f};
    float acc_p[8] = {0.f, 0.f, 0.f, 0.f, 0.f, 0.f, 0.f, 0.f};
    float ps = 0.f;
    const float* Xr = &Xl[pxid * SROW];
    const float* Pr = &Pl[pxid * SROW];

    #pragma unroll 2
    for (int ch = 0; ch < CCH; ch += 4) {
        float4 xv = *(const float4*)&Xr[ch];
        float4 pv = *(const float4*)&Pr[ch];
        ps += xv.x * pv.x + xv.y * pv.y + xv.z * pv.z + xv.w * pv.w;
        #pragma unroll
        for (int r = 0; r < 8; ++r) {
            float4 sv = *(const float4*)&Sl[(ktid + r * 8) * SROW + ch];
            acc_i[r] += sv.x * xv.x + sv.y * xv.y + sv.z * xv.z + sv.w * xv.w;
            acc_p[r] += sv.x * pv.x + sv.y * pv.y + sv.z * pv.z + sv.w * pv.w;
        }
    }

    float si = 0.f, spp = 0.f;
    #pragma unroll
    for (int r = 0; r < 8; ++r) {
        si  += expf(acc_i[r] * TAU_INV);
        spp += expf(acc_p[r] * TAU_INV);
    }
    // reduce over the 8 ktid lanes (consecutive within the wave)
    #pragma unroll
    for (int off = 1; off < 8; off <<= 1) {
        si  += __shfl_xor(si, off);
        spp += __shfl_xor(spp, off);
    }

    float v = 0.f;
    if (ktid == 0 && (start + pxid) < count) {
        si  -= (float)(KPAD - KSEL);   // remove exp(0)=1 of the 14 zero rows
        spp -= (float)(KPAD - KSEL);
        float nom = expf(ps * TAU_INV);
        float li = -logf(nom / (si + nom + EPSL));
        float lp = -logf(nom / (spp + nom + EPSL));
        v = (li + lp) * (1.0f / (float)NPIX);
    }
    v += __shfl_xor(v, 8);
    v += __shfl_xor(v, 16);
    v += __shfl_xor(v, 32);
    int w = t >> 6;
    if ((t & 63) == 0) bsum[w] = v;
    __syncthreads();
    if (t == 0) atomicAdd(out, bsum[0] + bsum[1] + bsum[2] + bsum[3]);
}

// ---------------------------------------------------------------------------
extern "C" void kernel_launch(void* const* d_in, const int* in_sizes, int n_in,
                              void* d_out, int out_size, void* d_ws, size_t ws_size,
                              hipStream_t stream) {
    const float* input      = (const float*)d_in[0];
    const float* positive   = (const float*)d_in[1];
    const float* negative   = (const float*)d_in[2];
    const float* in_logits  = (const float*)d_in[3];
    const float* neg_logits = (const float*)d_in[4];
    float* out = (float*)d_out;

    float* ws    = (float*)d_ws;
    float* ni    = ws;                             // [N*C]
    float* np_   = ws + 1048576;                   // [N*C]
    float* nnsel = ws + 2097152;                   // [4*50*C]
    int*   cnt   = (int*)(ws + 3145728);           // [4] (pad 64)
    int*   perm  = cnt + 64;                       // [4*N]

    prep_kernel<<<256 + NCLS, 256, 0, stream>>>(input, positive, negative,
                                                in_logits, neg_logits,
                                                ni, np_, nnsel, perm, cnt, out);
    dim3 lgrid(NPIX / PXT, NCLS);
    loss_kernel<<<lgrid, 256, 0, stream>>>(ni, np_, nnsel, perm, cnt, out);
}

// Round 5
// 104.178 us; speedup vs baseline: 1.0520x; 1.0520x over previous
//
#include <hip/hip_runtime.h>
#include <math.h>

#define TAU_INV (1.0f / 0.07f)
#define KSEL 50
#define KPAD 64      // zero-padded rows 50..63: dot=0 -> exp=1 -> subtract 14
#define NPIX 8192
#define CCH 128
#define HWSZ 4096
#define NCLS 4
#define EPSL 1e-8f
#define NBINS 1026
#define PXT 32       // pixels per loss block
#define SROW 132     // LDS row stride in floats

// ---------------------------------------------------------------------------
// Kernel 1: per class c (one block, 1024 threads): inline seg/softmax from
// the logits (8 consecutive px per thread), histogram top-50 select (proven
// round-0 logic), atomic-free same-class bucketing via block scan (perm is
// globally ascending -> locality for the loss gathers), then gather+normalize
// the 50 selected negative columns into compact nnsel[c*50+r][128].
// The full norm+transpose of all three tensors is GONE: negative needs only
// 50 columns/class; input/positive are normalized on the fly in kernel 2.
// ---------------------------------------------------------------------------
__global__ void __launch_bounds__(1024) topk_kernel(
        const float* __restrict__ ilog, const float* __restrict__ nlog,
        const float* __restrict__ negative,
        float* __restrict__ nnsel, int* __restrict__ perm, int* __restrict__ cnt,
        float* __restrict__ out) {
    __shared__ unsigned hist[NBINS];
    __shared__ unsigned coarse[33];
    __shared__ unsigned long long cand[2048];
    __shared__ unsigned wsum[16];
    __shared__ int topk_l[KPAD];
    __shared__ unsigned above_cnt, cand_cnt;
    __shared__ int sB, sc0;

    int c = blockIdx.x, t = threadIdx.x;
    if (c == 0 && t == 0) out[0] = 0.0f;

    for (int i = t; i < NBINS; i += 1024) hist[i] = 0;
    if (t < 33) coarse[t] = 0;
    if (t == 0) { above_cnt = 0; cand_cnt = 0; }
    __syncthreads();

    // Phase 1: inline seg -> histogram + same-class membership bitmask.
    // Thread t owns pixels 8t..8t+7 (two float4 groups), so the scan-ordered
    // perm below is globally ascending.
    unsigned keys[8];
    unsigned mask = 0u;
    #pragma unroll
    for (int s = 0; s < 2; ++s) {
        int i4 = (t * 2 + s) * 4;
        int b = i4 >> 12, hw = i4 & (HWSZ - 1);

        const float* pi = ilog + (size_t)b * NCLS * HWSZ + hw;
        float4 a0 = *(const float4*)&pi[0];
        float4 a1 = *(const float4*)&pi[HWSZ];
        float4 a2 = *(const float4*)&pi[2 * HWSZ];
        float4 a3 = *(const float4*)&pi[3 * HWSZ];
        const float* pn = nlog + (size_t)b * NCLS * HWSZ + hw;
        float4 b0 = *(const float4*)&pn[0];
        float4 b1 = *(const float4*)&pn[HWSZ];
        float4 b2 = *(const float4*)&pn[2 * HWSZ];
        float4 b3 = *(const float4*)&pn[3 * HWSZ];

        const float* A0 = (const float*)&a0; const float* A1 = (const float*)&a1;
        const float* A2 = (const float*)&a2; const float* A3 = (const float*)&a3;
        const float* B0 = (const float*)&b0; const float* B1 = (const float*)&b1;
        const float* B2 = (const float*)&b2; const float* B3 = (const float*)&b3;
        #pragma unroll
        for (int j = 0; j < 4; ++j) {
            float l0 = A0[j], l1 = A1[j], l2 = A2[j], l3 = A3[j];
            int bi = 0; float bv = l0;
            if (l1 > bv) { bv = l1; bi = 1; }
            if (l2 > bv) { bv = l2; bi = 2; }
            if (l3 > bv) { bv = l3; bi = 3; }
            if (bi == c) mask |= (1u << (s * 4 + j));

            float m0 = B0[j], m1 = B1[j], m2 = B2[j], m3 = B3[j];
            int ci = 0; float cv = m0;
            if (m1 > cv) { cv = m1; ci = 1; }
            if (m2 > cv) { cv = m2; ci = 2; }
            if (m3 > cv) { cv = m3; ci = 3; }
            float ssum = expf(m0 - cv) + expf(m1 - cv) + expf(m2 - cv) + expf(m3 - cv);
            float npv = 1.0f / ssum;

            float v = (ci != c) ? npv : 0.0f;
            unsigned key = __float_as_uint(v);
            keys[s * 4 + j] = key;
            int bin = (key < 0x3E800000u) ? 0 : (int)(1u + ((key - 0x3E800000u) >> 14));
            atomicAdd(&hist[bin], 1u);
        }
    }

    // Phase 1b: atomic-free bucketing. Wave-level inclusive scan of per-thread
    // popcounts + per-wave totals; emission in ascending pixel order.
    {
        int cnt_t = __popc(mask);
        int lane = t & 63, wv = t >> 6;
        int x = cnt_t;
        #pragma unroll
        for (int off = 1; off < 64; off <<= 1) {
            int o = __shfl_up(x, off);
            if (lane >= off) x += o;
        }
        if (lane == 63) wsum[wv] = (unsigned)x;
        __syncthreads();                 // wsum ready; hist atomics also done
        int base = x - cnt_t;
        for (int ww = 0; ww < wv; ++ww) base += (int)wsum[ww];
        unsigned mm = mask;
        while (mm) {
            int bit = __ffs(mm) - 1; mm &= (mm - 1);
            perm[c * NPIX + base] = t * 8 + bit;   // px = 8t + bit, ascending
            ++base;
        }
        if (t == 0) {
            int tot = 0;
            for (int w2 = 0; w2 < 16; ++w2) tot += (int)wsum[w2];
            cnt[c] = tot;
        }
    }

    // Phase 2a: coarse sums (32 bins per chunk)
    for (int i = t; i < NBINS; i += 1024) atomicAdd(&coarse[i >> 5], hist[i]);
    __syncthreads();

    // Phase 2b: two-level serial scan from the top (proven round-0 logic)
    if (t == 0) {
        unsigned cum = 0; int j = 32;
        for (; j > 0; --j) {
            unsigned h = coarse[j];
            if (cum + h >= KSEL) break;
            cum += h;
        }
        int hi = j * 32 + 31; if (hi > NBINS - 1) hi = NBINS - 1;
        int B = 0;
        for (int b = hi; b >= j * 32; --b) {
            unsigned h = hist[b];
            if (cum + h >= KSEL) { B = b; break; }
            cum += h;
        }
        sB = B; sc0 = (int)cum;   // cum = count strictly above bin B (< 50)
    }
    __syncthreads();
    int B = sB, c0 = sc0;

    // Phase 3: emit definite winners (LDS); collect boundary-bin candidates
    #pragma unroll
    for (int s = 0; s < 2; ++s) {
        #pragma unroll
        for (int j = 0; j < 4; ++j) {
            unsigned key = keys[s * 4 + j];
            int bin = (key < 0x3E800000u) ? 0 : (int)(1u + ((key - 0x3E800000u) >> 14));
            int i = t * 8 + s * 4 + j;
            if (bin > B) {
                unsigned pos = atomicAdd(&above_cnt, 1u);
                topk_l[pos] = i;
            } else if (bin == B) {
                unsigned jj = atomicAdd(&cand_cnt, 1u);
                if (jj < 2048)
                    cand[jj] = ((unsigned long long)key << 32) |
                               (unsigned long long)(0xFFFFFFFFu - (unsigned)i);
            }
        }
    }
    __syncthreads();

    // Phase 4: wave 0 picks remaining (50 - c0) best boundary candidates
    int m = KSEL - c0;
    int cb = (int)cand_cnt; if (cb > 2048) cb = 2048;
    if (t < 64) {
        for (int r = 0; r < m; ++r) {
            unsigned long long best = 0;
            for (int j = t; j < cb; j += 64) {
                unsigned long long v = cand[j];
                if (v > best) best = v;
            }
            #pragma unroll
            for (int off = 32; off; off >>= 1) {
                unsigned long long o = __shfl_xor(best, off);
                if (o > best) best = o;
            }
            if (t == 0) topk_l[c0 + r] =
                (int)(0xFFFFFFFFu - (unsigned)(best & 0xFFFFFFFFull));
            for (int j = t; j < cb; j += 64)
                if (cand[j] == best) cand[j] = 0;
        }
    }
    __syncthreads();

    // Phase 5: gather + normalize the 50 winners into nnsel[c*50+row][128].
    // 16 threads per row, 8 ch each; 16-lane shuffle reduce (within a wave).
    {
        int row = t >> 4;
        int ch0 = (t & 15) * 8;
        if (row < KSEL) {
            int px = topk_l[row];
            int b = px >> 12, hw = px & (HWSZ - 1);
            const float* src = negative + (size_t)b * CCH * HWSZ + hw;
            float vals[8]; float ss = 0.f;
            #pragma unroll
            for (int k = 0; k < 8; ++k) {
                float v = src[(size_t)(ch0 + k) * HWSZ];
                vals[k] = v; ss += v * v;
            }
            ss += __shfl_xor(ss, 1);
            ss += __shfl_xor(ss, 2);
            ss += __shfl_xor(ss, 4);
            ss += __shfl_xor(ss, 8);
            float inv = 1.0f / fmaxf(sqrtf(ss), 1e-12f);
            float* dst = nnsel + (size_t)(c * KSEL + row) * CCH + ch0;
            #pragma unroll
            for (int k = 0; k < 8; ++k) dst[k] = vals[k] * inv;
        }
    }
}

// ---------------------------------------------------------------------------
// Kernel 2: same-class GEMM-style loss.  Block = 32 pixels of one class.
// X/P are gathered from the RAW input/positive tensors (L2/L3-resident,
// 16 MB total) and normalized in-block: 8 threads per pixel, 16 ch each,
// 8-lane shuffle reduce for the norm.  GEMM core unchanged (proven).
// ---------------------------------------------------------------------------
__global__ void __launch_bounds__(256) loss_kernel(
        const float* __restrict__ input, const float* __restrict__ positive,
        const float* __restrict__ nnsel,
        const int* __restrict__ perm, const int* __restrict__ cnt,
        float* __restrict__ out) {
    __shared__ float Sl[KPAD * SROW];   // 33792 B
    __shared__ float Xl[PXT * SROW];    // 16896 B
    __shared__ float Pl[PXT * SROW];    // 16896 B
    __shared__ float bsum[4];

    int c = blockIdx.y;
    int count = cnt[c];
    int start = blockIdx.x * PXT;
    if (start >= count) return;
    int t = threadIdx.x;

    // stage S: 4 threads per row, 32 ch each (rows 50..63 zeroed)
    {
        int row = t >> 2;
        int ch0 = (t & 3) * 32;
        float* dst = &Sl[row * SROW + ch0];
        if (row < KSEL) {
            const float* src = nnsel + (size_t)(c * KSEL + row) * CCH + ch0;
            #pragma unroll
            for (int i = 0; i < 8; ++i)
                ((float4*)dst)[i] = ((const float4*)src)[i];
        } else {
            float4 z = make_float4(0.f, 0.f, 0.f, 0.f);
            #pragma unroll
            for (int i = 0; i < 8; ++i)
                ((float4*)dst)[i] = z;
        }
    }
    // stage X, P: gather + normalize.  8 threads per pixel row, 16 ch each.
    {
        int row = t >> 3;
        int slot = start + row;
        int px = perm[c * NPIX + ((slot < count) ? slot : start)];
        int b = px >> 12, hw = px & (HWSZ - 1);
        int ch0 = (t & 7) * 16;
        const float* bx = input    + (size_t)b * CCH * HWSZ + hw;
        const float* bp = positive + (size_t)b * CCH * HWSZ + hw;
        float xv[16], pv[16];
        float ssx = 0.f, ssp = 0.f;
        #pragma unroll
        for (int k = 0; k < 16; ++k) {
            float vx = bx[(size_t)(ch0 + k) * HWSZ];
            float vp = bp[(size_t)(ch0 + k) * HWSZ];
            xv[k] = vx; ssx += vx * vx;
            pv[k] = vp; ssp += vp * vp;
        }
        // reduce over the 8 lanes of this pixel (lanes 8r..8r+7, same wave)
        ssx += __shfl_xor(ssx, 1); ssp += __shfl_xor(ssp, 1);
        ssx += __shfl_xor(ssx, 2); ssp += __shfl_xor(ssp, 2);
        ssx += __shfl_xor(ssx, 4); ssp += __shfl_xor(ssp, 4);
        float ix = 1.0f / fmaxf(sqrtf(ssx), 1e-12f);
        float ip = 1.0f / fmaxf(sqrtf(ssp), 1e-12f);
        float* dx = &Xl[row * SROW + ch0];
        float* dp = &Pl[row * SROW + ch0];
        #pragma unroll
        for (int i = 0; i < 4; ++i) {
            float4 ox = make_float4(xv[4*i+0]*ix, xv[4*i+1]*ix,
                                    xv[4*i+2]*ix, xv[4*i+3]*ix);
            float4 op = make_float4(pv[4*i+0]*ip, pv[4*i+1]*ip,
                                    pv[4*i+2]*ip, pv[4*i+3]*ip);
            ((float4*)dx)[i] = ox;
            ((float4*)dp)[i] = op;
        }
    }
    __syncthreads();

    int ktid = t & 7, pxid = t >> 3;
    float acc_i[8] = {0.f, 0.f, 0.f, 0.f, 0.f, 0.f, 0.f, 0.f};
    float acc_p[8] = {0.f, 0.f, 0.f, 0.f, 0.f, 0.f, 0.f, 0.f};
    float ps = 0.f;
    const float* Xr = &Xl[pxid * SROW];
    const float* Pr = &Pl[pxid * SROW];

    #pragma unroll 2
    for (int ch = 0; ch < CCH; ch += 4) {
        float4 xv = *(const float4*)&Xr[ch];
        float4 pv = *(const float4*)&Pr[ch];
        ps += xv.x * pv.x + xv.y * pv.y + xv.z * pv.z + xv.w * pv.w;
        #pragma unroll
        for (int r = 0; r < 8; ++r) {
            float4 sv = *(const float4*)&Sl[(ktid + r * 8) * SROW + ch];
            acc_i[r] += sv.x * xv.x + sv.y * xv.y + sv.z * xv.z + sv.w * xv.w;
            acc_p[r] += sv.x * pv.x + sv.y * pv.y + sv.z * pv.z + sv.w * pv.w;
        }
    }

    float si = 0.f, spp = 0.f;
    #pragma unroll
    for (int r = 0; r < 8; ++r) {
        si  += expf(acc_i[r] * TAU_INV);
        spp += expf(acc_p[r] * TAU_INV);
    }
    // reduce over the 8 ktid lanes (consecutive within the wave)
    #pragma unroll
    for (int off = 1; off < 8; off <<= 1) {
        si  += __shfl_xor(si, off);
        spp += __shfl_xor(spp, off);
    }

    float v = 0.f;
    if (ktid == 0 && (start + pxid) < count) {
        si  -= (float)(KPAD - KSEL);   // remove exp(0)=1 of the 14 zero rows
        spp -= (float)(KPAD - KSEL);
        float nom = expf(ps * TAU_INV);
        float li = -logf(nom / (si + nom + EPSL));
        float lp = -logf(nom / (spp + nom + EPSL));
        v = (li + lp) * (1.0f / (float)NPIX);
    }
    v += __shfl_xor(v, 8);
    v += __shfl_xor(v, 16);
    v += __shfl_xor(v, 32);
    int w = t >> 6;
    if ((t & 63) == 0) bsum[w] = v;
    __syncthreads();
    if (t == 0) atomicAdd(out, bsum[0] + bsum[1] + bsum[2] + bsum[3]);
}

// ---------------------------------------------------------------------------
extern "C" void kernel_launch(void* const* d_in, const int* in_sizes, int n_in,
                              void* d_out, int out_size, void* d_ws, size_t ws_size,
                              hipStream_t stream) {
    const float* input      = (const float*)d_in[0];
    const float* positive   = (const float*)d_in[1];
    const float* negative   = (const float*)d_in[2];
    const float* in_logits  = (const float*)d_in[3];
    const float* neg_logits = (const float*)d_in[4];
    float* out = (float*)d_out;

    float* ws    = (float*)d_ws;
    float* nnsel = ws;                             // [4*50*128] (pad 32768)
    int*   cnt   = (int*)(ws + 32768);             // [4] (pad 64)
    int*   perm  = cnt + 64;                       // [4*N]

    topk_kernel<<<NCLS, 1024, 0, stream>>>(in_logits, neg_logits, negative,
                                           nnsel, perm, cnt, out);
    dim3 lgrid(NPIX / PXT, NCLS);
    loss_kernel<<<lgrid, 256, 0, stream>>>(input, positive, nnsel,
                                           perm, cnt, out);
}